// Round 14
// baseline (87.696 us; speedup 1.0000x reference)
//
#include <hip/hip_runtime.h>

// out = atoms_x - segment_mean(atoms_x, graph_batch)[graph_batch], gb SORTED.
// TWO-KERNEL SPLIT, no halo reads anywhere:
//  K1 (stream): per-wave chunked loads -> per-lane run accumulation -> LDS
//     slot table -> flush to global ws[mol]={sx,sy,sz,cnt}: plain float4
//     store for INTERIOR molecules (provably exclusive to this chunk),
//     atomicAdd only for the 2 edge molecules (~62K atomics total).
//     Interior atoms' means are known locally -> subtract + store them NOW.
//  K2 (tiny): per chunk, fix only the edge-run atoms (~80/chunk) using the
//     completed ws (kernel boundary guarantees visibility).
// ws zeroed via hipMemsetAsync each call (graph-capture safe).

static constexpr int WAVE   = 64;
static constexpr int WPB    = 4;                 // independent waves / WG
static constexpr int TPB    = WAVE * WPB;
static constexpr int CPT    = 16;                // atoms per lane
static constexpr int WCHUNK = WAVE * CPT;        // 1024 atoms per wave
static constexpr int SLOTS  = 128;               // id-span per chunk (exp ~27)
static constexpr int M_MOLS = 200000;

#define LDS_FENCE() asm volatile("s_waitcnt lgkmcnt(0)" ::: "memory")

// ------------------------------- K1: sums + interior subtract -------------
__global__ __launch_bounds__(TPB) void k1_sum_interior(
    const float* __restrict__ x, const int* __restrict__ gb,
    float* __restrict__ ws, float* __restrict__ out, int n) {
  __shared__ float sums_all[WPB][SLOTS * 4];

  const int w = threadIdx.x >> 6;
  const int lane = threadIdx.x & 63;
  float* sums = sums_all[w];

  const long long cs = ((long long)blockIdx.x * WPB + w) * WCHUNK;
  if (cs >= (long long)n) return;  // no barriers anywhere -> safe
  const long long ce = (cs + WCHUNK < (long long)n) ? cs + WCHUNK : (long long)n;

  if (ce - cs < WCHUNK) {
    // ---- tail chunk: atomic everything; K2's tail path stores all atoms ----
    for (long long i = cs + lane; i < ce; i += WAVE) {
      int id = gb[i];
      atomicAdd(&ws[(size_t)id * 4 + 0], x[i * 3 + 0]);
      atomicAdd(&ws[(size_t)id * 4 + 1], x[i * 3 + 1]);
      atomicAdd(&ws[(size_t)id * 4 + 2], x[i * 3 + 2]);
      atomicAdd(&ws[(size_t)id * 4 + 3], 1.f);
    }
    return;
  }

  const long long base = cs + (long long)lane * CPT;

  // ---- chunked vector loads (r9's proven path) ----
  float f[CPT * 3];
  int ids[CPT];
  {
    const float4* xv = reinterpret_cast<const float4*>(x + base * 3);
#pragma unroll
    for (int j = 0; j < CPT * 3 / 4; ++j) {
      float4 v = xv[j];
      f[j * 4 + 0] = v.x; f[j * 4 + 1] = v.y;
      f[j * 4 + 2] = v.z; f[j * 4 + 3] = v.w;
    }
    const int4* gv = reinterpret_cast<const int4*>(gb + base);
#pragma unroll
    for (int j = 0; j < CPT / 4; ++j) {
      int4 g = gv[j];
      ids[j * 4 + 0] = g.x; ids[j * 4 + 1] = g.y;
      ids[j * 4 + 2] = g.z; ids[j * 4 + 3] = g.w;
    }
  }
  const int fid = __shfl(ids[0], 0);
  const int lid = __shfl(ids[CPT - 1], WAVE - 1);
  const int span = lid - fid + 1;

  if (span > SLOTS) {
    // Pathological id-sparsity; wave-uniform, never hot, correct.
    if (lane == 0) {
      long long i = cs;
      while (i < ce) {
        int id = gb[i];
        long long re = i;
        float sx = 0.f, sy = 0.f, sz = 0.f;
        while (re < ce && gb[re] == id) {
          sx += x[re*3+0]; sy += x[re*3+1]; sz += x[re*3+2]; ++re;
        }
        float cnt = (float)(re - i);
        atomicAdd(&ws[(size_t)id*4+0], sx);
        atomicAdd(&ws[(size_t)id*4+1], sy);
        atomicAdd(&ws[(size_t)id*4+2], sz);
        atomicAdd(&ws[(size_t)id*4+3], cnt);
        if (id != fid && id != lid) {  // interior run: complete locally
          float inv = 1.f / cnt;
          float mx = sx*inv, my = sy*inv, mz = sz*inv;
          for (long long k = i; k < re; ++k) {
            out[k*3+0] = x[k*3+0] - mx;
            out[k*3+1] = x[k*3+1] - my;
            out[k*3+2] = x[k*3+2] - mz;
          }
        }
        i = re;
      }
    }
    return;
  }

  // ---- zero slot table ----
  for (int i = lane; i < span * 4; i += WAVE) sums[i] = 0.f;
  LDS_FENCE();

  // ---- per-lane run accumulation, flush at id boundaries ----
  {
    int cur = ids[0];
    float sx = 0.f, sy = 0.f, sz = 0.f, sc = 0.f;
#pragma unroll
    for (int j = 0; j < CPT; ++j) {
      if (ids[j] != cur) {
        int s = (cur - fid) * 4;
        atomicAdd(&sums[s + 0], sx); atomicAdd(&sums[s + 1], sy);
        atomicAdd(&sums[s + 2], sz); atomicAdd(&sums[s + 3], sc);
        cur = ids[j]; sx = sy = sz = sc = 0.f;
      }
      sx += f[j * 3 + 0]; sy += f[j * 3 + 1]; sz += f[j * 3 + 2]; sc += 1.f;
    }
    int s = (cur - fid) * 4;
    atomicAdd(&sums[s + 0], sx); atomicAdd(&sums[s + 1], sy);
    atomicAdd(&sums[s + 2], sz); atomicAdd(&sums[s + 3], sc);
  }
  LDS_FENCE();

  // ---- flush slots to ws: edges atomic, interior plain (exclusive) ----
  for (int s = lane; s < span; s += WAVE) {
    float4 v = *reinterpret_cast<float4*>(&sums[s * 4]);
    size_t mol = (size_t)(fid + s) * 4;
    if (s == 0 || s == span - 1) {
      atomicAdd(&ws[mol + 0], v.x); atomicAdd(&ws[mol + 1], v.y);
      atomicAdd(&ws[mol + 2], v.z); atomicAdd(&ws[mol + 3], v.w);
    } else {
      *reinterpret_cast<float4*>(&ws[mol]) = v;  // exclusive molecule
    }
  }

  // ---- interior slots -> means (in LDS) ----
  for (int s = lane; s < span; s += WAVE) {
    if (s > 0 && s < span - 1) {
      float c = sums[s * 4 + 3];
      if (c > 0.f) {
        float inv = 1.f / c;
        sums[s*4+0] *= inv; sums[s*4+1] *= inv; sums[s*4+2] *= inv;
      }
    }
  }
  LDS_FENCE();

  // ---- subtract + store INTERIOR atoms (edge atoms left to K2) ----
  if (ids[0] != fid && ids[CPT - 1] != lid) {
    // all 16 atoms interior (sorted) -> full vector path
#pragma unroll
    for (int j = 0; j < CPT; ++j) {
      int s = (ids[j] - fid) * 4;
      f[j * 3 + 0] -= sums[s + 0];
      f[j * 3 + 1] -= sums[s + 1];
      f[j * 3 + 2] -= sums[s + 2];
    }
    float4* ov = reinterpret_cast<float4*>(out + base * 3);
#pragma unroll
    for (int j = 0; j < CPT * 3 / 4; ++j)
      ov[j] = make_float4(f[j * 4 + 0], f[j * 4 + 1],
                          f[j * 4 + 2], f[j * 4 + 3]);
  } else {
    // edge lane: per-atom masked scalar stores
#pragma unroll
    for (int j = 0; j < CPT; ++j) {
      int id = ids[j];
      if (id != fid && id != lid) {
        int s = (id - fid) * 4;
        long long i = base + j;
        out[i * 3 + 0] = f[j * 3 + 0] - sums[s + 0];
        out[i * 3 + 1] = f[j * 3 + 1] - sums[s + 1];
        out[i * 3 + 2] = f[j * 3 + 2] - sums[s + 2];
      }
    }
  }
}

// ------------------------------- K2: edge-run fix-up ----------------------
__global__ __launch_bounds__(TPB) void k2_edges(
    const float* __restrict__ x, const int* __restrict__ gb,
    const float* __restrict__ ws, float* __restrict__ out, int n) {
  const int w = threadIdx.x >> 6;
  const int lane = threadIdx.x & 63;

  const long long cs = ((long long)blockIdx.x * WPB + w) * WCHUNK;
  if (cs >= (long long)n) return;
  const long long ce = (cs + WCHUNK < (long long)n) ? cs + WCHUNK : (long long)n;

  if (ce - cs < WCHUNK) {
    // ---- tail chunk: K1 only accumulated; store ALL atoms here ----
    for (long long i = cs + lane; i < ce; i += WAVE) {
      int id = gb[i];
      float4 v = *reinterpret_cast<const float4*>(&ws[(size_t)id * 4]);
      float inv = 1.f / v.w;  // id present -> count >= 1
      out[i * 3 + 0] = x[i * 3 + 0] - v.x * inv;
      out[i * 3 + 1] = x[i * 3 + 1] - v.y * inv;
      out[i * 3 + 2] = x[i * 3 + 2] - v.z * inv;
    }
    return;
  }

  const int fid = gb[cs];
  const int lid = gb[ce - 1];

  // ---- front run (id == fid) ----
  {
    float4 v = *reinterpret_cast<const float4*>(&ws[(size_t)fid * 4]);
    float inv = 1.f / v.w;
    float mx = v.x * inv, my = v.y * inv, mz = v.z * inv;
    long long i = cs + lane;
    for (;;) {
      bool m = (i < ce) && (gb[i] == fid);
      if (m) {
        out[i * 3 + 0] = x[i * 3 + 0] - mx;
        out[i * 3 + 1] = x[i * 3 + 1] - my;
        out[i * 3 + 2] = x[i * 3 + 2] - mz;
      }
      if (__popcll(__ballot(m)) < WAVE) break;
      i += WAVE;
    }
  }
  // ---- back run (id == lid), skip if same molecule as front ----
  if (lid != fid) {
    float4 v = *reinterpret_cast<const float4*>(&ws[(size_t)lid * 4]);
    float inv = 1.f / v.w;
    float mx = v.x * inv, my = v.y * inv, mz = v.z * inv;
    long long i = ce - 1 - lane;
    for (;;) {
      bool m = (i >= cs) && (gb[i] == lid);
      if (m) {
        out[i * 3 + 0] = x[i * 3 + 0] - mx;
        out[i * 3 + 1] = x[i * 3 + 1] - my;
        out[i * 3 + 2] = x[i * 3 + 2] - mz;
      }
      if (__popcll(__ballot(m)) < WAVE) break;
      i -= WAVE;
    }
  }
}

extern "C" void kernel_launch(void* const* d_in, const int* in_sizes, int n_in,
                              void* d_out, int out_size, void* d_ws, size_t ws_size,
                              hipStream_t stream) {
  const float* x = (const float*)d_in[0];
  const int* gb = (const int*)d_in[1];
  float* out = (float*)d_out;
  float* ws = (float*)d_ws;  // [M_MOLS][4] = {sx, sy, sz, cnt}
  const int n = in_sizes[0] / 3;  // atoms

  hipMemsetAsync(ws, 0, (size_t)M_MOLS * 4 * sizeof(float), stream);

  long long nchunks = ((long long)n + WCHUNK - 1) / WCHUNK;
  int blocks = (int)((nchunks + WPB - 1) / WPB);
  k1_sum_interior<<<blocks, TPB, 0, stream>>>(x, gb, ws, out, n);
  k2_edges<<<blocks, TPB, 0, stream>>>(x, gb, ws, out, n);
}

// Round 15
// 55.883 us; speedup vs baseline: 1.5693x; 1.5693x over previous
//
#include <hip/hip_runtime.h>

// out = atoms_x - segment_mean(atoms_x, graph_batch)[graph_batch], gb SORTED.
// r9 structure (best, 53.2us): fused single pass, 4 INDEPENDENT waves/WG
// (no __syncthreads), per-lane run accumulation -> per-wave LDS slot table,
// ballot halo completion, chunked float4 loads/stores.
// Round-15 deltas ONLY:
//  - CPT 16->8 (512-atom chunks): 3907 WGs -> per-CU imbalance halves;
//    VGPR ~60->~44 -> more resident waves.
//  - Halo probes HOISTED: gb[cs-1-lane]/gb[ce+lane] issued with the main
//    load burst, masked x-halo loads issued BEFORE the accumulate -> the
//    accumulate hides the halo round-trip (was the unhidden tail of every
//    wave's critical path). Only the rare >=64-atom-run continuation loops
//    remain dependent.

static constexpr int WAVE   = 64;
static constexpr int WPB    = 4;                 // independent waves / WG
static constexpr int TPB    = WAVE * WPB;
static constexpr int CPT    = 8;                 // atoms per lane
static constexpr int WCHUNK = WAVE * CPT;        // 512 atoms per wave
static constexpr int SLOTS  = 64;                // id-span per chunk (exp ~13)

#define LDS_FENCE() asm volatile("s_waitcnt lgkmcnt(0)" ::: "memory")

__device__ void serial_fallback(const float* __restrict__ x,
                                const int* __restrict__ gb,
                                float* __restrict__ out, int n,
                                long long cs, long long ce, int lane) {
  // Pathological id-sparsity; wave-uniform, never hot, correct.
  if (lane != 0) return;
  long long i = cs;
  while (i < ce) {
    int id = gb[i];
    long long rs = i; while (rs > 0 && gb[rs - 1] == id) --rs;
    long long re = i; while (re < n && gb[re] == id) ++re;
    float sx = 0.f, sy = 0.f, sz = 0.f;
    for (long long k = rs; k < re; ++k) {
      sx += x[k * 3 + 0]; sy += x[k * 3 + 1]; sz += x[k * 3 + 2];
    }
    float inv = 1.f / (float)(re - rs);
    float mx = sx * inv, my = sy * inv, mz = sz * inv;
    long long we = (re < ce) ? re : ce;
    for (long long k = i; k < we; ++k) {
      out[k * 3 + 0] = x[k * 3 + 0] - mx;
      out[k * 3 + 1] = x[k * 3 + 1] - my;
      out[k * 3 + 2] = x[k * 3 + 2] - mz;
    }
    i = we;
  }
}

__global__ __launch_bounds__(TPB) void fused_center_kernel(
    const float* __restrict__ x, const int* __restrict__ gb,
    float* __restrict__ out, int n) {
  __shared__ float sums_all[WPB][SLOTS * 4];  // 1 KB per wave

  const int w = threadIdx.x >> 6;
  const int lane = threadIdx.x & 63;
  float* sums = sums_all[w];

  const long long cs = ((long long)blockIdx.x * WPB + w) * WCHUNK;
  if (cs >= (long long)n) return;  // idle wave; no barriers anywhere
  const long long ce = (cs + WCHUNK < (long long)n) ? cs + WCHUNK : (long long)n;

  if (ce - cs < WCHUNK) {
    // ---- partial tail chunk (at most one wave in the grid) ----
    const int fid = gb[cs];
    const int lid = gb[ce - 1];
    const int span = lid - fid + 1;
    if (span > SLOTS) { serial_fallback(x, gb, out, n, cs, ce, lane); return; }
    for (int s = lane; s < span * 4; s += WAVE) sums[s] = 0.f;
    LDS_FENCE();
    for (long long i = cs + lane; i < ce; i += WAVE) {
      int s = (gb[i] - fid) * 4;
      atomicAdd(&sums[s + 0], x[i * 3 + 0]);
      atomicAdd(&sums[s + 1], x[i * 3 + 1]);
      atomicAdd(&sums[s + 2], x[i * 3 + 2]);
      atomicAdd(&sums[s + 3], 1.f);
    }
    if (cs > 0) {  // front halo only (ce == n here)
      float hx = 0.f, hy = 0.f, hz = 0.f, hc = 0.f;
      long long off = 1 + lane;
      for (;;) {
        long long i = cs - off;
        bool m = (i >= 0) && (gb[i] == fid);
        if (m) { hx += x[i*3+0]; hy += x[i*3+1]; hz += x[i*3+2]; hc += 1.f; }
        if (__popcll(__ballot(m)) < WAVE) break;
        off += WAVE;
      }
#pragma unroll
      for (int d = 1; d < 64; d <<= 1) {
        hx += __shfl_xor(hx, d); hy += __shfl_xor(hy, d);
        hz += __shfl_xor(hz, d); hc += __shfl_xor(hc, d);
      }
      if (lane == 0 && hc > 0.f) {
        atomicAdd(&sums[0], hx); atomicAdd(&sums[1], hy);
        atomicAdd(&sums[2], hz); atomicAdd(&sums[3], hc);
      }
    }
    LDS_FENCE();
    for (int s = lane; s < span; s += WAVE) {
      float c = sums[s * 4 + 3];
      if (c > 0.f) {
        float inv = 1.f / c;
        sums[s*4+0] *= inv; sums[s*4+1] *= inv; sums[s*4+2] *= inv;
      }
    }
    LDS_FENCE();
    for (long long i = cs + lane; i < ce; i += WAVE) {
      int s = (gb[i] - fid) * 4;
      out[i * 3 + 0] = x[i * 3 + 0] - sums[s + 0];
      out[i * 3 + 1] = x[i * 3 + 1] - sums[s + 1];
      out[i * 3 + 2] = x[i * 3 + 2] - sums[s + 2];
    }
    return;
  }

  const long long base = cs + (long long)lane * CPT;

  // ---- main load burst (chunked float4/int4) ----
  float f[CPT * 3];
  int ids[CPT];
  {
    const float4* xv = reinterpret_cast<const float4*>(x + base * 3);
#pragma unroll
    for (int j = 0; j < CPT * 3 / 4; ++j) {
      float4 v = xv[j];
      f[j * 4 + 0] = v.x; f[j * 4 + 1] = v.y;
      f[j * 4 + 2] = v.z; f[j * 4 + 3] = v.w;
    }
    const int4* gv = reinterpret_cast<const int4*>(gb + base);
#pragma unroll
    for (int j = 0; j < CPT / 4; ++j) {
      int4 g = gv[j];
      ids[j * 4 + 0] = g.x; ids[j * 4 + 1] = g.y;
      ids[j * 4 + 2] = g.z; ids[j * 4 + 3] = g.w;
    }
  }

  // ---- HOISTED halo probes (issued with the main burst, no dependency) ----
  const bool hasF = (cs > 0);
  const bool hasB = (ce < (long long)n);
  int pf = -1, pb = -1;
  if (hasF) pf = gb[cs - 1 - lane];                       // cs>=512 -> in range
  if (hasB && ce + lane < (long long)n) pb = gb[ce + lane];

  // zero slot table (one float4 per lane)
  reinterpret_cast<float4*>(sums)[lane] = make_float4(0.f, 0.f, 0.f, 0.f);
  LDS_FENCE();

  const int fid = __shfl(ids[0], 0);
  const int lid = __shfl(ids[CPT - 1], WAVE - 1);
  const int span = lid - fid + 1;
  if (span > SLOTS) { serial_fallback(x, gb, out, n, cs, ce, lane); return; }

  // ---- issue masked x-halo loads BEFORE the accumulate (latency hidden) ----
  const bool mf = hasF && (pf == fid);
  const bool mb = hasB && (pb == lid);
  float fhx = 0.f, fhy = 0.f, fhz = 0.f, fhc = 0.f;
  if (mf) {
    long long i = cs - 1 - lane;
    fhx = x[i * 3 + 0]; fhy = x[i * 3 + 1]; fhz = x[i * 3 + 2]; fhc = 1.f;
  }
  float bhx = 0.f, bhy = 0.f, bhz = 0.f, bhc = 0.f;
  if (mb) {
    long long i = ce + lane;
    bhx = x[i * 3 + 0]; bhy = x[i * 3 + 1]; bhz = x[i * 3 + 2]; bhc = 1.f;
  }

  // ---- per-lane run accumulation, flush at id boundaries ----
  {
    int cur = ids[0];
    float sx = 0.f, sy = 0.f, sz = 0.f, sc = 0.f;
#pragma unroll
    for (int j = 0; j < CPT; ++j) {
      if (ids[j] != cur) {
        int s = (cur - fid) * 4;
        atomicAdd(&sums[s + 0], sx); atomicAdd(&sums[s + 1], sy);
        atomicAdd(&sums[s + 2], sz); atomicAdd(&sums[s + 3], sc);
        cur = ids[j]; sx = sy = sz = sc = 0.f;
      }
      sx += f[j * 3 + 0]; sy += f[j * 3 + 1]; sz += f[j * 3 + 2]; sc += 1.f;
    }
    int s = (cur - fid) * 4;
    atomicAdd(&sums[s + 0], sx); atomicAdd(&sums[s + 1], sy);
    atomicAdd(&sums[s + 2], sz); atomicAdd(&sums[s + 3], sc);
  }

  // ---- front halo: continuation (rare: run >= 64) + reduce + flush ----
  if (hasF) {
    unsigned long long bal = __ballot(mf);
    long long off = (long long)WAVE + 1 + lane;
    while (__popcll(bal) == WAVE) {
      long long i = cs - off;
      bool m2 = (i >= 0) && (gb[i] == fid);
      if (m2) {
        fhx += x[i*3+0]; fhy += x[i*3+1]; fhz += x[i*3+2]; fhc += 1.f;
      }
      bal = __ballot(m2);
      off += WAVE;
    }
#pragma unroll
    for (int d = 1; d < 64; d <<= 1) {
      fhx += __shfl_xor(fhx, d); fhy += __shfl_xor(fhy, d);
      fhz += __shfl_xor(fhz, d); fhc += __shfl_xor(fhc, d);
    }
    if (lane == 0 && fhc > 0.f) {
      atomicAdd(&sums[0], fhx); atomicAdd(&sums[1], fhy);
      atomicAdd(&sums[2], fhz); atomicAdd(&sums[3], fhc);
    }
  }
  // ---- back halo ----
  if (hasB) {
    unsigned long long bal = __ballot(mb);
    long long off = (long long)WAVE + lane;
    while (__popcll(bal) == WAVE) {
      long long i = ce + off;
      bool m2 = (i < (long long)n) && (gb[i] == lid);
      if (m2) {
        bhx += x[i*3+0]; bhy += x[i*3+1]; bhz += x[i*3+2]; bhc += 1.f;
      }
      bal = __ballot(m2);
      off += WAVE;
    }
#pragma unroll
    for (int d = 1; d < 64; d <<= 1) {
      bhx += __shfl_xor(bhx, d); bhy += __shfl_xor(bhy, d);
      bhz += __shfl_xor(bhz, d); bhc += __shfl_xor(bhc, d);
    }
    if (lane == 0 && bhc > 0.f) {
      int s = (lid - fid) * 4;
      atomicAdd(&sums[s + 0], bhx); atomicAdd(&sums[s + 1], bhy);
      atomicAdd(&sums[s + 2], bhz); atomicAdd(&sums[s + 3], bhc);
    }
  }
  LDS_FENCE();

  // ---- sums -> means (span <= 64: one slot per lane) ----
  if (lane < span) {
    float c = sums[lane * 4 + 3];
    if (c > 0.f) {
      float inv = 1.f / c;
      sums[lane*4+0] *= inv; sums[lane*4+1] *= inv; sums[lane*4+2] *= inv;
    }
  }
  LDS_FENCE();

  // ---- subtract + chunked float4 stores ----
#pragma unroll
  for (int j = 0; j < CPT; ++j) {
    int s = (ids[j] - fid) * 4;
    f[j * 3 + 0] -= sums[s + 0];
    f[j * 3 + 1] -= sums[s + 1];
    f[j * 3 + 2] -= sums[s + 2];
  }
  float4* ov = reinterpret_cast<float4*>(out + base * 3);
#pragma unroll
  for (int j = 0; j < CPT * 3 / 4; ++j)
    ov[j] = make_float4(f[j * 4 + 0], f[j * 4 + 1],
                        f[j * 4 + 2], f[j * 4 + 3]);
}

extern "C" void kernel_launch(void* const* d_in, const int* in_sizes, int n_in,
                              void* d_out, int out_size, void* d_ws, size_t ws_size,
                              hipStream_t stream) {
  const float* x = (const float*)d_in[0];
  const int* gb = (const int*)d_in[1];
  float* out = (float*)d_out;
  const int n = in_sizes[0] / 3;  // atoms

  long long nchunks = ((long long)n + WCHUNK - 1) / WCHUNK;
  int blocks = (int)((nchunks + WPB - 1) / WPB);
  fused_center_kernel<<<blocks, TPB, 0, stream>>>(x, gb, out, n);
}